// Round 2
// baseline (1540.358 us; speedup 1.0000x reference)
//
#include <hip/hip_runtime.h>
#include <math.h>

// clDice loss: 16 x 1 x 1024 x 1024 fp32 inputs, scalar fp32 output.
// Fused per-iteration kernel: erode(5-pt cross) -> dilate(3x3) -> GELU skel
// update, all through LDS tiles. Reductions via block partials + atomicAdd.

#define HH 1024
#define WW 1024
#define NIMG 16
constexpr int IMG_ELEMS = HH * WW;          // 1048576
constexpr int TOTAL = NIMG * IMG_ELEMS;     // 16777216
constexpr int BLK = 256;

constexpr int TILE_W = 64;
constexpr int TILE_H = 16;
constexpr int IN_W = TILE_W + 4;   // 68 (halo 2 each side)
constexpr int IN_H = TILE_H + 4;   // 20
constexpr int ER_W = TILE_W + 2;   // 66 (halo 1)
constexpr int ER_H = TILE_H + 2;   // 18

__device__ __forceinline__ float gelu_f(float x) {
    // exact (erf) gelu, matches jax.nn.gelu(approximate=False)
    return 0.5f * x * (1.0f + erff(x * 0.70710678118654752440f));
}

// MODE 0: skel = gelu(X - dilate(erode(X))); write eOut = erode(X)
// MODE 1: delta = gelu(X - dilate(erode(X))); skel += gelu(delta - skel*delta);
//         write eOut
// MODE 2: same skel update but DO NOT write skel or eOut; instead reduce
//         sum(skel_new) and sum(skel_new * other) -> atomicAdd acc[0], acc[1]
// DICE (only with MODE 0, phase 1): other = y_true; also reduce per-image
//         sigmoid-dice sums into acc[4+img], acc[20+img], acc[36+img]
template <int MODE, bool DICE>
__global__ __launch_bounds__(BLK) void fused_step(
        const float* __restrict__ X,
        float* __restrict__ eOut,
        float* __restrict__ skel,
        const float* __restrict__ other,
        float* __restrict__ acc) {
    __shared__ float sIn[IN_H][IN_W];
    __shared__ float sEr[ER_H][ER_W];

    const int x0 = blockIdx.x * TILE_W;
    const int y0 = blockIdx.y * TILE_H;
    const int img = blockIdx.z;
    const size_t base = (size_t)img * IMG_ELEMS;
    const int tid = threadIdx.x;

    // ---- load input tile with clamp-to-edge (correct for erode's +inf pad)
    for (int i = tid; i < IN_H * IN_W; i += BLK) {
        int ly = i / IN_W, lx = i - ly * IN_W;
        int gy = y0 - 2 + ly; gy = min(max(gy, 0), HH - 1);
        int gx = x0 - 2 + lx; gx = min(max(gx, 0), WW - 1);
        sIn[ly][lx] = X[base + (size_t)gy * WW + gx];
    }
    __syncthreads();

    // ---- erode (5-point cross min) over tile + halo 1.
    // Positions outside the image must be -inf so the subsequent dilate
    // ignores them (reference pads dilate with -inf; edge-replicated erode
    // values in the halo would be WRONG here).
    for (int i = tid; i < ER_H * ER_W; i += BLK) {
        int ey = i / ER_W, ex = i - ey * ER_W;
        int iy = y0 - 1 + ey, ix = x0 - 1 + ex;
        float v;
        if (iy < 0 || iy >= HH || ix < 0 || ix >= WW) {
            v = -INFINITY;
        } else {
            v = sIn[ey + 1][ex + 1];
            v = fminf(v, sIn[ey    ][ex + 1]);
            v = fminf(v, sIn[ey + 2][ex + 1]);
            v = fminf(v, sIn[ey + 1][ex    ]);
            v = fminf(v, sIn[ey + 1][ex + 2]);
        }
        sEr[ey][ex] = v;
    }
    __syncthreads();

    // ---- dilate (3x3 max) + skel update (+ optional reductions)
    float a0 = 0.f, a1 = 0.f;            // MODE 2: sum(s), sum(s*other)
    float d0 = 0.f, d1 = 0.f, d2 = 0.f;  // DICE: inter, sum(sigmoid), sum(t)
    for (int j = tid; j < TILE_H * TILE_W; j += BLK) {
        int oy = j >> 6, ox = j & 63;    // TILE_W == 64
        size_t gidx = base + (size_t)(y0 + oy) * WW + (x0 + ox);

        float m =      sEr[oy    ][ox];
        m = fmaxf(m,   sEr[oy    ][ox + 1]);
        m = fmaxf(m,   sEr[oy    ][ox + 2]);
        m = fmaxf(m,   sEr[oy + 1][ox]);
        m = fmaxf(m,   sEr[oy + 1][ox + 1]);
        m = fmaxf(m,   sEr[oy + 1][ox + 2]);
        m = fmaxf(m,   sEr[oy + 2][ox]);
        m = fmaxf(m,   sEr[oy + 2][ox + 1]);
        m = fmaxf(m,   sEr[oy + 2][ox + 2]);

        float prev = sIn[oy + 2][ox + 2];
        float delta = gelu_f(prev - m);
        float s;
        if (MODE == 0) {
            s = delta;
        } else {
            float s0 = skel[gidx];
            s = s0 + gelu_f(delta - s0 * delta);
        }
        if (MODE != 2) {
            skel[gidx] = s;
            eOut[gidx] = sEr[oy + 1][ox + 1];
        } else {
            float o = other[gidx];
            a0 += s;
            a1 += s * o;
        }
        if (DICE) {
            float t = other[gidx];
            float pv = 1.0f / (1.0f + expf(-prev));
            d0 += pv * t;
            d1 += pv;
            d2 += t;
        }
    }

    if (MODE == 2 || DICE) {
        __shared__ float sh[20];
        int wave = tid >> 6;
        int lane = tid & 63;
        if (MODE == 2) {
            for (int o = 32; o > 0; o >>= 1) {
                a0 += __shfl_down(a0, o, 64);
                a1 += __shfl_down(a1, o, 64);
            }
            if (lane == 0) { sh[wave] = a0; sh[4 + wave] = a1; }
        }
        if (DICE) {
            for (int o = 32; o > 0; o >>= 1) {
                d0 += __shfl_down(d0, o, 64);
                d1 += __shfl_down(d1, o, 64);
                d2 += __shfl_down(d2, o, 64);
            }
            if (lane == 0) { sh[8 + wave] = d0; sh[12 + wave] = d1; sh[16 + wave] = d2; }
        }
        __syncthreads();
        if (tid == 0) {
            if (MODE == 2) {
                atomicAdd(&acc[0], sh[0] + sh[1] + sh[2] + sh[3]);
                atomicAdd(&acc[1], sh[4] + sh[5] + sh[6] + sh[7]);
            }
            if (DICE) {
                atomicAdd(&acc[4 + img],  sh[8]  + sh[9]  + sh[10] + sh[11]);
                atomicAdd(&acc[20 + img], sh[12] + sh[13] + sh[14] + sh[15]);
                atomicAdd(&acc[36 + img], sh[16] + sh[17] + sh[18] + sh[19]);
            }
        }
    }
}

// acc layout: [0]=sum skelP, [1]=sum skelP*true   (phase1, accP base = acc)
//             [2]=sum skelT, [3]=sum skelT*pred   (phase2, accT base = acc+2)
//             [4..19]=inter, [20..35]=sum sigmoid(p), [36..51]=sum t
__global__ void final_combine(const float* __restrict__ acc,
                              float* __restrict__ out) {
    if (threadIdx.x != 0) return;
    float sumP  = acc[0];
    float sumPt = acc[1];
    float sumT  = acc[2];
    float sumTp = acc[3];

    const float SMOOTH = 1.0f;
    float tprec = (sumPt + SMOOTH) / (sumP + SMOOTH);
    float tsens = (sumTp + SMOOTH) / (sumT + SMOOTH);
    float cl_dice = 1.0f - 2.0f * (tprec * tsens) / (tprec + tsens);

    const float EPS = 1e-4f;
    float dsum = 0.f;
    for (int n = 0; n < NIMG; n++) {
        float inter = acc[4 + n];
        float sp    = acc[20 + n];
        float st    = acc[36 + n];
        float gd = (2.0f * inter + EPS) / (sp + st + EPS);
        dsum += 1.0f - gd;
    }
    float dice = dsum / (float)NIMG;
    out[0] = 0.5f * cl_dice + 0.5f * dice;
}

extern "C" void kernel_launch(void* const* d_in, const int* in_sizes, int n_in,
                              void* d_out, int out_size, void* d_ws, size_t ws_size,
                              hipStream_t stream) {
    const float* y_pred = (const float*)d_in[0];
    const float* y_true = (const float*)d_in[1];
    float* out = (float*)d_out;

    float* skel = (float*)d_ws;
    float* eA   = skel + TOTAL;
    float* eB   = eA + TOTAL;
    float* acc  = eB + TOTAL;   // 52 floats

    hipMemsetAsync(acc, 0, 52 * sizeof(float), stream);

    dim3 grd(WW / TILE_W, HH / TILE_H, NIMG);   // 16 x 64 x 16 = 16384 blocks
    dim3 blk(BLK);

    // ---- phase 1: skel(y_pred); reduce sum(skelP), sum(skelP*y_true); dice fused
    fused_step<0, true ><<<grd, blk, 0, stream>>>(y_pred, eA, skel, y_true, acc);
    fused_step<1, false><<<grd, blk, 0, stream>>>(eA, eB, skel, nullptr, nullptr);
    fused_step<1, false><<<grd, blk, 0, stream>>>(eB, eA, skel, nullptr, nullptr);
    fused_step<2, false><<<grd, blk, 0, stream>>>(eA, nullptr, skel, y_true, acc);

    // ---- phase 2: skel(y_true); reduce sum(skelT), sum(skelT*y_pred)
    fused_step<0, false><<<grd, blk, 0, stream>>>(y_true, eA, skel, nullptr, nullptr);
    fused_step<1, false><<<grd, blk, 0, stream>>>(eA, eB, skel, nullptr, nullptr);
    fused_step<1, false><<<grd, blk, 0, stream>>>(eB, eA, skel, nullptr, nullptr);
    fused_step<2, false><<<grd, blk, 0, stream>>>(eA, nullptr, skel, y_pred, acc + 2);

    final_combine<<<1, 64, 0, stream>>>(acc, out);
}

// Round 3
// 514.974 us; speedup vs baseline: 2.9911x; 2.9911x over previous
//
#include <hip/hip_runtime.h>
#include <math.h>

// clDice loss: 16 x 1 x 1024 x 1024 fp32 inputs, scalar fp32 output.
// ONE fused kernel per phase: full erosion cascade (e1..e4) + dilate + GELU
// skel updates + all reductions, via LDS tiles with halo 5. No intermediate
// HBM traffic. Atomics spread over many cachelines to avoid serialization.

#define HH 1024
#define WW 1024
#define NIMG 16
constexpr int IMG_ELEMS = HH * WW;
constexpr int TILE_W = 128;
constexpr int TILE_H = 32;
constexpr int BLKT = 512;
constexpr int FR_W = TILE_W + 10;     // 138
constexpr int FR_H = TILE_H + 10;     // 42
constexpr int FRAME = FR_H * FR_W;    // 5796 floats
constexpr int NOUT = TILE_W * TILE_H; // 4096
constexpr int OPT = NOUT / BLKT;      // 8 outputs per thread
constexpr int PSLOTS = 128;           // spread slots for phase sums
constexpr int DSLOTS = 16;            // spread slots per image for dice sums
constexpr int GRID_X = WW / TILE_W;   // 8
constexpr int GRID_Y = HH / TILE_H;   // 32

__device__ __forceinline__ float gelu_f(float x) {
    // exact (erf) gelu, matches jax.nn.gelu(approximate=False)
    return 0.5f * x * (1.0f + erff(x * 0.70710678118654752440f));
}

// Erode level K (5-pt cross min) from S into D, both in the common frame
// (origin at global (y0-5, x0-5), pitch FR_W). Level K occupies
// rows/cols [K, FR-K). Clamp-to-edge indexing == +inf-pad erode; for edge
// blocks taps clamp to the image (clamped coords stay inside stored extent).
template <int K>
__device__ __forceinline__ void erode_level(const float* __restrict__ S,
                                            float* __restrict__ D,
                                            int tid, int y0, int x0, bool edge) {
    constexpr int Ck = FR_W - 2 * K;
    constexpr int Rk = FR_H - 2 * K;
    constexpr int n = Rk * Ck;
    if (!edge) {
        for (int i = tid; i < n; i += BLKT) {
            int r = i / Ck;
            int c = i - r * Ck;
            int o = (K + r) * FR_W + (K + c);
            float v = S[o];
            v = fminf(v, S[o - FR_W]);
            v = fminf(v, S[o + FR_W]);
            v = fminf(v, S[o - 1]);
            v = fminf(v, S[o + 1]);
            D[o] = v;
        }
    } else {
        for (int i = tid; i < n; i += BLKT) {
            int r = i / Ck;
            int c = i - r * Ck;
            int ly = K + r, lx = K + c;
            int gy = y0 - 5 + ly, gx = x0 - 5 + lx;
            int yc = min(max(gy, 0), HH - 1) - (y0 - 5);
            int ym = min(max(gy - 1, 0), HH - 1) - (y0 - 5);
            int yp = min(max(gy + 1, 0), HH - 1) - (y0 - 5);
            int xc = min(max(gx, 0), WW - 1) - (x0 - 5);
            int xm = min(max(gx - 1, 0), WW - 1) - (x0 - 5);
            int xp = min(max(gx + 1, 0), WW - 1) - (x0 - 5);
            float v = S[yc * FR_W + xc];
            v = fminf(v, S[ym * FR_W + xc]);
            v = fminf(v, S[yp * FR_W + xc]);
            v = fminf(v, S[yc * FR_W + xm]);
            v = fminf(v, S[yc * FR_W + xp]);
            D[ly * FR_W + lx] = v;
        }
    }
}

// 3x3 dilate at frame coord (ly,lx); output coords are always in-image.
// Clamp-to-edge == -inf-pad dilate for max pooling.
__device__ __forceinline__ float dilate_at(const float* __restrict__ Cb,
                                           int ly, int lx, int y0, int x0,
                                           bool edge) {
    if (!edge) {
        int o = ly * FR_W + lx;
        float m =      Cb[o - FR_W - 1];
        m = fmaxf(m,   Cb[o - FR_W]);
        m = fmaxf(m,   Cb[o - FR_W + 1]);
        m = fmaxf(m,   Cb[o - 1]);
        m = fmaxf(m,   Cb[o]);
        m = fmaxf(m,   Cb[o + 1]);
        m = fmaxf(m,   Cb[o + FR_W - 1]);
        m = fmaxf(m,   Cb[o + FR_W]);
        m = fmaxf(m,   Cb[o + FR_W + 1]);
        return m;
    } else {
        int gy = y0 - 5 + ly, gx = x0 - 5 + lx;
        int ym = min(max(gy - 1, 0), HH - 1) - (y0 - 5);
        int yp = min(max(gy + 1, 0), HH - 1) - (y0 - 5);
        int xm = min(max(gx - 1, 0), WW - 1) - (x0 - 5);
        int xp = min(max(gx + 1, 0), WW - 1) - (x0 - 5);
        float m =      Cb[ym * FR_W + xm];
        m = fmaxf(m,   Cb[ym * FR_W + lx]);
        m = fmaxf(m,   Cb[ym * FR_W + xp]);
        m = fmaxf(m,   Cb[ly * FR_W + xm]);
        m = fmaxf(m,   Cb[ly * FR_W + lx]);
        m = fmaxf(m,   Cb[ly * FR_W + xp]);
        m = fmaxf(m,   Cb[yp * FR_W + xm]);
        m = fmaxf(m,   Cb[yp * FR_W + lx]);
        m = fmaxf(m,   Cb[yp * FR_W + xp]);
        return m;
    }
}

// accP layout: PSLOTS cachelines of 32 floats, slot*32 + q:
//   q=0: sum skelP, q=1: sum skelP*true, q=2: sum skelT, q=3: sum skelT*pred
// accD layout: (img*DSLOTS + s)*32 + q: q=0 inter, q=1 sum sigmoid(p), q=2 sum t
template <bool PHASE1>
__global__ __launch_bounds__(BLKT) void cl_fused(
        const float* __restrict__ X,
        const float* __restrict__ other,
        float* __restrict__ accP,
        float* __restrict__ accD) {
    __shared__ float A[FRAME];
    __shared__ float B[FRAME];
    __shared__ float sh[40];

    const int x0 = blockIdx.x * TILE_W;
    const int y0 = blockIdx.y * TILE_H;
    const int img = blockIdx.z;
    const size_t base = (size_t)img * IMG_ELEMS;
    const int tid = threadIdx.x;
    const bool edge = (x0 == 0) || (y0 == 0) ||
                      (x0 + TILE_W == WW) || (y0 + TILE_H == HH);

    // ---- load X tile + halo 5 (clamp-to-edge)
    for (int i = tid; i < FRAME; i += BLKT) {
        int ly = i / FR_W, lx = i - ly * FR_W;
        int gy = min(max(y0 - 5 + ly, 0), HH - 1);
        int gx = min(max(x0 - 5 + lx, 0), WW - 1);
        A[i] = X[base + (size_t)gy * WW + gx];
    }
    __syncthreads();

    erode_level<1>(A, B, tid, y0, x0, edge);   // e1 -> B
    __syncthreads();

    float skel[OPT], oth[OPT];
    float d0 = 0.f, d1 = 0.f, d2 = 0.f;

    // ---- update 0: skel = gelu(X - dil(e1)); read `other`; fused dice
#pragma unroll
    for (int w = 0; w < OPT; w++) {
        int j = tid + w * BLKT;
        int oy = j >> 7, ox = j & 127;       // TILE_W == 128
        int ly = oy + 5, lx = ox + 5;
        float prev = A[ly * FR_W + lx];
        float m = dilate_at(B, ly, lx, y0, x0, edge);
        skel[w] = gelu_f(prev - m);
        float t = other[base + (size_t)(y0 + oy) * WW + (x0 + ox)];
        oth[w] = t;
        if (PHASE1) {
            float pv = 1.0f / (1.0f + expf(-prev));
            d0 += pv * t; d1 += pv; d2 += t;
        }
    }
    __syncthreads();

    erode_level<2>(B, A, tid, y0, x0, edge);   // e2 -> A
    __syncthreads();
#pragma unroll
    for (int w = 0; w < OPT; w++) {            // update 1: prev=e1(B), cur=e2(A)
        int j = tid + w * BLKT;
        int oy = j >> 7, ox = j & 127;
        int ly = oy + 5, lx = ox + 5;
        float prev = B[ly * FR_W + lx];
        float m = dilate_at(A, ly, lx, y0, x0, edge);
        float delta = gelu_f(prev - m);
        skel[w] += gelu_f(delta - skel[w] * delta);
    }
    __syncthreads();

    erode_level<3>(A, B, tid, y0, x0, edge);   // e3 -> B
    __syncthreads();
#pragma unroll
    for (int w = 0; w < OPT; w++) {            // update 2: prev=e2(A), cur=e3(B)
        int j = tid + w * BLKT;
        int oy = j >> 7, ox = j & 127;
        int ly = oy + 5, lx = ox + 5;
        float prev = A[ly * FR_W + lx];
        float m = dilate_at(B, ly, lx, y0, x0, edge);
        float delta = gelu_f(prev - m);
        skel[w] += gelu_f(delta - skel[w] * delta);
    }
    __syncthreads();

    erode_level<4>(B, A, tid, y0, x0, edge);   // e4 -> A
    __syncthreads();

    float a0 = 0.f, a1 = 0.f;
#pragma unroll
    for (int w = 0; w < OPT; w++) {            // update 3 (final): prev=e3(B), cur=e4(A)
        int j = tid + w * BLKT;
        int oy = j >> 7, ox = j & 127;
        int ly = oy + 5, lx = ox + 5;
        float prev = B[ly * FR_W + lx];
        float m = dilate_at(A, ly, lx, y0, x0, edge);
        float delta = gelu_f(prev - m);
        float s = skel[w] + gelu_f(delta - skel[w] * delta);
        a0 += s;
        a1 += s * oth[w];
    }

    // ---- block reduction: wave shuffle -> LDS -> spread atomics
    int wave = tid >> 6, lane = tid & 63;
    for (int o = 32; o > 0; o >>= 1) {
        a0 += __shfl_down(a0, o, 64);
        a1 += __shfl_down(a1, o, 64);
    }
    if (lane == 0) { sh[wave] = a0; sh[8 + wave] = a1; }
    if (PHASE1) {
        for (int o = 32; o > 0; o >>= 1) {
            d0 += __shfl_down(d0, o, 64);
            d1 += __shfl_down(d1, o, 64);
            d2 += __shfl_down(d2, o, 64);
        }
        if (lane == 0) { sh[16 + wave] = d0; sh[24 + wave] = d1; sh[32 + wave] = d2; }
    }
    __syncthreads();
    if (tid == 0) {
        float s0 = 0.f, s1 = 0.f;
        for (int wv = 0; wv < 8; wv++) { s0 += sh[wv]; s1 += sh[8 + wv]; }
        int lb = blockIdx.x + GRID_X * blockIdx.y;           // 0..255 within img
        int slot = (lb + img * 37) & (PSLOTS - 1);
        atomicAdd(&accP[slot * 32 + (PHASE1 ? 0 : 2)], s0);
        atomicAdd(&accP[slot * 32 + (PHASE1 ? 1 : 3)], s1);
        if (PHASE1) {
            float t0 = 0.f, t1 = 0.f, t2 = 0.f;
            for (int wv = 0; wv < 8; wv++) {
                t0 += sh[16 + wv]; t1 += sh[24 + wv]; t2 += sh[32 + wv];
            }
            float* dst = accD + (size_t)(img * DSLOTS + (lb & (DSLOTS - 1))) * 32;
            atomicAdd(&dst[0], t0);
            atomicAdd(&dst[1], t1);
            atomicAdd(&dst[2], t2);
        }
    }
}

__global__ __launch_bounds__(256) void final_combine(
        const float* __restrict__ accP,
        const float* __restrict__ accD,
        float* __restrict__ out) {
    __shared__ float shp[2][4];
    __shared__ float shd[NIMG][3];
    int tid = threadIdx.x;
    int lane = tid & 63, wave = tid >> 6;

    float p0 = 0.f, p1 = 0.f, p2 = 0.f, p3 = 0.f;
    if (tid < PSLOTS) {
        const float* s = accP + tid * 32;
        p0 = s[0]; p1 = s[1]; p2 = s[2]; p3 = s[3];
    }
    for (int o = 32; o > 0; o >>= 1) {
        p0 += __shfl_down(p0, o, 64); p1 += __shfl_down(p1, o, 64);
        p2 += __shfl_down(p2, o, 64); p3 += __shfl_down(p3, o, 64);
    }
    if (lane == 0 && wave < 2) {
        shp[wave][0] = p0; shp[wave][1] = p1; shp[wave][2] = p2; shp[wave][3] = p3;
    }

    int n = tid >> 4, s16 = tid & 15;
    const float* d = accD + (size_t)(n * DSLOTS + s16) * 32;
    float q0 = d[0], q1 = d[1], q2 = d[2];
    for (int o = 8; o > 0; o >>= 1) {
        q0 += __shfl_down(q0, o, 16);
        q1 += __shfl_down(q1, o, 16);
        q2 += __shfl_down(q2, o, 16);
    }
    if (s16 == 0) { shd[n][0] = q0; shd[n][1] = q1; shd[n][2] = q2; }
    __syncthreads();

    if (tid == 0) {
        float sumP  = shp[0][0] + shp[1][0];
        float sumPt = shp[0][1] + shp[1][1];
        float sumT  = shp[0][2] + shp[1][2];
        float sumTp = shp[0][3] + shp[1][3];
        const float SMOOTH = 1.0f;
        float tprec = (sumPt + SMOOTH) / (sumP + SMOOTH);
        float tsens = (sumTp + SMOOTH) / (sumT + SMOOTH);
        float cl = 1.0f - 2.0f * (tprec * tsens) / (tprec + tsens);
        const float EPS = 1e-4f;
        float dsum = 0.f;
        for (int k = 0; k < NIMG; k++) {
            float gd = (2.0f * shd[k][0] + EPS) / (shd[k][1] + shd[k][2] + EPS);
            dsum += 1.0f - gd;
        }
        out[0] = 0.5f * cl + 0.5f * (dsum / (float)NIMG);
    }
}

extern "C" void kernel_launch(void* const* d_in, const int* in_sizes, int n_in,
                              void* d_out, int out_size, void* d_ws, size_t ws_size,
                              hipStream_t stream) {
    const float* y_pred = (const float*)d_in[0];
    const float* y_true = (const float*)d_in[1];
    float* out = (float*)d_out;

    float* accP = (float*)d_ws;                  // 128*32 floats
    float* accD = accP + PSLOTS * 32;            // 16*16*32 floats

    hipMemsetAsync(accP, 0, (PSLOTS * 32 + NIMG * DSLOTS * 32) * sizeof(float),
                   stream);

    dim3 grd(GRID_X, GRID_Y, NIMG), blk(BLKT);   // 8 x 32 x 16 = 4096 blocks
    // phase 1: X=y_pred, other=y_true (+ fused sigmoid-dice sums)
    cl_fused<true ><<<grd, blk, 0, stream>>>(y_pred, y_true, accP, accD);
    // phase 2: X=y_true, other=y_pred
    cl_fused<false><<<grd, blk, 0, stream>>>(y_true, y_pred, accP, accD);
    final_combine<<<1, 256, 0, stream>>>(accP, accD, out);
}

// Round 4
// 380.412 us; speedup vs baseline: 4.0492x; 1.3537x over previous
//
#include <hip/hip_runtime.h>
#include <math.h>

// clDice loss: 16 x 1 x 1024 x 1024 fp32 inputs, scalar fp32 output.
// Single fused kernel (both phases, z=0..31): full erosion cascade e1..e4 +
// separable dilate + fast-GELU skel updates + reductions, all in LDS.
// Out-of-image halo handled by a cheap replication fix-up pass (edge blocks
// only), preserving exact +/-inf pooling-pad semantics.

#define HH 1024
#define WW 1024
#define NIMG 16
constexpr int IMG_ELEMS = HH * WW;
constexpr int TILE_W = 128;
constexpr int TILE_H = 32;
constexpr int BLKT = 512;
constexpr int FR_W = TILE_W + 10;     // 138
constexpr int FR_H = TILE_H + 10;     // 42
constexpr int FRAME = FR_H * FR_W;    // 5796 floats
constexpr int PSLOTS = 128;
constexpr int DSLOTS = 16;
constexpr int GRID_X = WW / TILE_W;   // 8
constexpr int GRID_Y = HH / TILE_H;   // 32

// ---- fast math: A&S 7.1.26 erf (|eps|<=1.5e-7) with v_exp_f32 / v_rcp_f32
__device__ __forceinline__ float gelu_fast(float x) {
    float z = x * 0.70710678118654752440f;
    float az = fabsf(z);
    float t = __builtin_amdgcn_rcpf(fmaf(az, 0.3275911f, 1.0f));
    float e = __expf(-az * az);
    float p = fmaf(1.061405429f, t, -1.453152027f);
    p = fmaf(p, t, 1.421413741f);
    p = fmaf(p, t, -0.284496736f);
    p = fmaf(p, t, 0.254829592f);
    p = p * t;
    float E = fmaf(-p, e, 1.0f);           // erf(|z|)
    float erf_s = copysignf(E, x);
    return 0.5f * x * (1.0f + erf_s);
}

__device__ __forceinline__ float sigmoid_fast(float x) {
    return __builtin_amdgcn_rcpf(1.0f + __expf(-x));
}

// ---- erode level K (5-pt cross min), fast interior formula everywhere.
// Out-of-image cells get garbage here; fixed by fixup_level afterwards.
template <int K>
__device__ __forceinline__ void erode_fast(const float* __restrict__ S,
                                           float* __restrict__ D, int tid) {
    constexpr int Ck = FR_W - 2 * K;
    constexpr int Rk = FR_H - 2 * K;
    constexpr int n = Rk * Ck;
    for (int i = tid; i < n; i += BLKT) {
        int r = i / Ck;
        int c = i - r * Ck;
        int o = (K + r) * FR_W + (K + c);
        float v = fminf(fminf(S[o - FR_W], S[o]), S[o + FR_W]);
        D[o] = fminf(v, fminf(S[o - 1], S[o + 1]));
    }
}

// Replicate clamped in-image values into out-of-image cells of level K's
// extent. Writes only out-of-image cells, reads only in-image cells: no
// intra-pass race. (clamp-to-edge replication == +inf/-inf pad semantics
// for the downstream min/max consumers.)
template <int K>
__device__ __forceinline__ void fixup_level(float* __restrict__ D, int tid,
                                            int y0, int x0) {
    constexpr int Ck = FR_W - 2 * K;
    constexpr int Rk = FR_H - 2 * K;
    constexpr int n = Rk * Ck;
    for (int i = tid; i < n; i += BLKT) {
        int r = i / Ck;
        int c = i - r * Ck;
        int ly = K + r, lx = K + c;
        int gy = y0 - 5 + ly, gx = x0 - 5 + lx;
        if (gy < 0 || gy >= HH || gx < 0 || gx >= WW) {
            int cly = min(max(gy, 0), HH - 1) - (y0 - 5);
            int clx = min(max(gx, 0), WW - 1) - (x0 - 5);
            D[ly * FR_W + lx] = D[cly * FR_W + clx];
        }
    }
}

// accP: PSLOTS cachelines of 32 floats: slot*32 + {0:sumP,1:sumP*t,2:sumT,3:sumT*p}
// accD: (img*DSLOTS + s)*32 + {0:inter, 1:sum sigmoid(p), 2:sum t}
__global__ __launch_bounds__(BLKT) void cl_fused(
        const float* __restrict__ y_pred,
        const float* __restrict__ y_true,
        float* __restrict__ accP,
        float* __restrict__ accD) {
    __shared__ float A[FRAME];
    __shared__ float B[FRAME];
    __shared__ float sh[40];

    const int x0 = blockIdx.x * TILE_W;
    const int y0 = blockIdx.y * TILE_H;
    const bool PH1 = blockIdx.z < NIMG;
    const int img = blockIdx.z & (NIMG - 1);
    const float* __restrict__ X  = PH1 ? y_pred : y_true;
    const float* __restrict__ OT = PH1 ? y_true : y_pred;
    const size_t base = (size_t)img * IMG_ELEMS;
    const int tid = threadIdx.x;
    const bool edge = (x0 == 0) || (y0 == 0) ||
                      (x0 + TILE_W == WW) || (y0 + TILE_H == HH);

    // strip mapping for updates: thread owns column c, rows rs..rs+7
    const int c = tid & (TILE_W - 1);
    const int rs = (tid >> 7) * 8;

    // ---- load X tile + halo 5 (clamp-to-edge == replicated values)
    for (int i = tid; i < FRAME; i += BLKT) {
        int ly = i / FR_W, lx = i - ly * FR_W;
        int gy = min(max(y0 - 5 + ly, 0), HH - 1);
        int gx = min(max(x0 - 5 + lx, 0), WW - 1);
        A[i] = X[base + (size_t)gy * WW + gx];
    }
    __syncthreads();

    float skel[8], oth[8];
    float d0 = 0.f, d1 = 0.f, d2 = 0.f;

    // ================ level 1 ================
    erode_fast<1>(A, B, tid);
    __syncthreads();
    if (edge) { fixup_level<1>(B, tid, y0, x0); __syncthreads(); }

    // update 0: skel = gelu(X - dil(e1)); fused other-read + dice
    {
        float m0, m1, m2;
        {
            int o = (4 + rs) * FR_W + (4 + c);
            m0 = fmaxf(fmaxf(B[o], B[o + 1]), B[o + 2]);
            o += FR_W;
            m1 = fmaxf(fmaxf(B[o], B[o + 1]), B[o + 2]);
        }
#pragma unroll
        for (int r = 0; r < 8; r++) {
            int o = (6 + rs + r) * FR_W + (4 + c);
            m2 = fmaxf(fmaxf(B[o], B[o + 1]), B[o + 2]);
            float dil = fmaxf(fmaxf(m0, m1), m2);
            float prev = A[(5 + rs + r) * FR_W + (5 + c)];
            skel[r] = gelu_fast(prev - dil);
            float t = OT[base + (size_t)(y0 + rs + r) * WW + (x0 + c)];
            oth[r] = t;
            if (PH1) {
                float pv = sigmoid_fast(prev);
                d0 += pv * t; d1 += pv; d2 += t;
            }
            m0 = m1; m1 = m2;
        }
    }
    __syncthreads();

    // ================ level 2 ================
    erode_fast<2>(B, A, tid);
    __syncthreads();
    if (edge) { fixup_level<2>(A, tid, y0, x0); __syncthreads(); }
    {
        float m0, m1, m2;
        {
            int o = (4 + rs) * FR_W + (4 + c);
            m0 = fmaxf(fmaxf(A[o], A[o + 1]), A[o + 2]);
            o += FR_W;
            m1 = fmaxf(fmaxf(A[o], A[o + 1]), A[o + 2]);
        }
#pragma unroll
        for (int r = 0; r < 8; r++) {
            int o = (6 + rs + r) * FR_W + (4 + c);
            m2 = fmaxf(fmaxf(A[o], A[o + 1]), A[o + 2]);
            float dil = fmaxf(fmaxf(m0, m1), m2);
            float prev = B[(5 + rs + r) * FR_W + (5 + c)];
            float delta = gelu_fast(prev - dil);
            skel[r] += gelu_fast(delta - skel[r] * delta);
            m0 = m1; m1 = m2;
        }
    }
    __syncthreads();

    // ================ level 3 ================
    erode_fast<3>(A, B, tid);
    __syncthreads();
    if (edge) { fixup_level<3>(B, tid, y0, x0); __syncthreads(); }
    {
        float m0, m1, m2;
        {
            int o = (4 + rs) * FR_W + (4 + c);
            m0 = fmaxf(fmaxf(B[o], B[o + 1]), B[o + 2]);
            o += FR_W;
            m1 = fmaxf(fmaxf(B[o], B[o + 1]), B[o + 2]);
        }
#pragma unroll
        for (int r = 0; r < 8; r++) {
            int o = (6 + rs + r) * FR_W + (4 + c);
            m2 = fmaxf(fmaxf(B[o], B[o + 1]), B[o + 2]);
            float dil = fmaxf(fmaxf(m0, m1), m2);
            float prev = A[(5 + rs + r) * FR_W + (5 + c)];
            float delta = gelu_fast(prev - dil);
            skel[r] += gelu_fast(delta - skel[r] * delta);
            m0 = m1; m1 = m2;
        }
    }
    __syncthreads();

    // ================ level 4 (final; reduce, no stores) ================
    erode_fast<4>(B, A, tid);
    __syncthreads();
    if (edge) { fixup_level<4>(A, tid, y0, x0); __syncthreads(); }

    float a0 = 0.f, a1 = 0.f;
    {
        float m0, m1, m2;
        {
            int o = (4 + rs) * FR_W + (4 + c);
            m0 = fmaxf(fmaxf(A[o], A[o + 1]), A[o + 2]);
            o += FR_W;
            m1 = fmaxf(fmaxf(A[o], A[o + 1]), A[o + 2]);
        }
#pragma unroll
        for (int r = 0; r < 8; r++) {
            int o = (6 + rs + r) * FR_W + (4 + c);
            m2 = fmaxf(fmaxf(A[o], A[o + 1]), A[o + 2]);
            float dil = fmaxf(fmaxf(m0, m1), m2);
            float prev = B[(5 + rs + r) * FR_W + (5 + c)];
            float delta = gelu_fast(prev - dil);
            float s = skel[r] + gelu_fast(delta - skel[r] * delta);
            a0 += s;
            a1 += s * oth[r];
            m0 = m1; m1 = m2;
        }
    }

    // ---- block reduction: wave shuffle -> LDS -> spread atomics
    int wave = tid >> 6, lane = tid & 63;
    for (int o = 32; o > 0; o >>= 1) {
        a0 += __shfl_down(a0, o, 64);
        a1 += __shfl_down(a1, o, 64);
    }
    if (lane == 0) { sh[wave] = a0; sh[8 + wave] = a1; }
    if (PH1) {
        for (int o = 32; o > 0; o >>= 1) {
            d0 += __shfl_down(d0, o, 64);
            d1 += __shfl_down(d1, o, 64);
            d2 += __shfl_down(d2, o, 64);
        }
        if (lane == 0) { sh[16 + wave] = d0; sh[24 + wave] = d1; sh[32 + wave] = d2; }
    }
    __syncthreads();
    if (tid == 0) {
        float s0 = 0.f, s1 = 0.f;
        for (int wv = 0; wv < 8; wv++) { s0 += sh[wv]; s1 += sh[8 + wv]; }
        int lb = blockIdx.x + GRID_X * blockIdx.y;
        int slot = (lb + blockIdx.z * 37) & (PSLOTS - 1);
        atomicAdd(&accP[slot * 32 + (PH1 ? 0 : 2)], s0);
        atomicAdd(&accP[slot * 32 + (PH1 ? 1 : 3)], s1);
        if (PH1) {
            float t0 = 0.f, t1 = 0.f, t2 = 0.f;
            for (int wv = 0; wv < 8; wv++) {
                t0 += sh[16 + wv]; t1 += sh[24 + wv]; t2 += sh[32 + wv];
            }
            float* dst = accD + (size_t)(img * DSLOTS + (lb & (DSLOTS - 1))) * 32;
            atomicAdd(&dst[0], t0);
            atomicAdd(&dst[1], t1);
            atomicAdd(&dst[2], t2);
        }
    }
}

__global__ __launch_bounds__(256) void final_combine(
        const float* __restrict__ accP,
        const float* __restrict__ accD,
        float* __restrict__ out) {
    __shared__ float shp[2][4];
    __shared__ float shd[NIMG][3];
    int tid = threadIdx.x;
    int lane = tid & 63, wave = tid >> 6;

    float p0 = 0.f, p1 = 0.f, p2 = 0.f, p3 = 0.f;
    if (tid < PSLOTS) {
        const float* s = accP + tid * 32;
        p0 = s[0]; p1 = s[1]; p2 = s[2]; p3 = s[3];
    }
    for (int o = 32; o > 0; o >>= 1) {
        p0 += __shfl_down(p0, o, 64); p1 += __shfl_down(p1, o, 64);
        p2 += __shfl_down(p2, o, 64); p3 += __shfl_down(p3, o, 64);
    }
    if (lane == 0 && wave < 2) {
        shp[wave][0] = p0; shp[wave][1] = p1; shp[wave][2] = p2; shp[wave][3] = p3;
    }

    int n = tid >> 4, s16 = tid & 15;
    const float* d = accD + (size_t)(n * DSLOTS + s16) * 32;
    float q0 = d[0], q1 = d[1], q2 = d[2];
    for (int o = 8; o > 0; o >>= 1) {
        q0 += __shfl_down(q0, o, 16);
        q1 += __shfl_down(q1, o, 16);
        q2 += __shfl_down(q2, o, 16);
    }
    if (s16 == 0) { shd[n][0] = q0; shd[n][1] = q1; shd[n][2] = q2; }
    __syncthreads();

    if (tid == 0) {
        float sumP  = shp[0][0] + shp[1][0];
        float sumPt = shp[0][1] + shp[1][1];
        float sumT  = shp[0][2] + shp[1][2];
        float sumTp = shp[0][3] + shp[1][3];
        const float SMOOTH = 1.0f;
        float tprec = (sumPt + SMOOTH) / (sumP + SMOOTH);
        float tsens = (sumTp + SMOOTH) / (sumT + SMOOTH);
        float cl = 1.0f - 2.0f * (tprec * tsens) / (tprec + tsens);
        const float EPS = 1e-4f;
        float dsum = 0.f;
        for (int k = 0; k < NIMG; k++) {
            float gd = (2.0f * shd[k][0] + EPS) / (shd[k][1] + shd[k][2] + EPS);
            dsum += 1.0f - gd;
        }
        out[0] = 0.5f * cl + 0.5f * (dsum / (float)NIMG);
    }
}

extern "C" void kernel_launch(void* const* d_in, const int* in_sizes, int n_in,
                              void* d_out, int out_size, void* d_ws, size_t ws_size,
                              hipStream_t stream) {
    const float* y_pred = (const float*)d_in[0];
    const float* y_true = (const float*)d_in[1];
    float* out = (float*)d_out;

    float* accP = (float*)d_ws;                  // 128*32 floats
    float* accD = accP + PSLOTS * 32;            // 16*16*32 floats

    hipMemsetAsync(accP, 0, (PSLOTS * 32 + NIMG * DSLOTS * 32) * sizeof(float),
                   stream);

    dim3 grd(GRID_X, GRID_Y, 2 * NIMG), blk(BLKT);   // 8192 blocks, both phases
    cl_fused<<<grd, blk, 0, stream>>>(y_pred, y_true, accP, accD);
    final_combine<<<1, 256, 0, stream>>>(accP, accD, out);
}